// Round 5
// baseline (86.306 us; speedup 1.0000x reference)
//
#include <hip/hip_runtime.h>

#define DIM     400
#define D4      100
#define B       32
#define NCAND   14505
#define CT      32
#define NCT     454     // ceil(NCAND / CT)
#define HF4     50      // float4 per D-half (200 dims)
#define THREADS 256

// ---- setup (ws path): qg[b] = ent[head_b] + relc[rel_b]; baseg[b] = one + 0.98*sum(relo[rel_b])
__global__ void setup_kernel(const float* __restrict__ ent,
                             const float* __restrict__ relc,
                             const float* __restrict__ relo,
                             const float* __restrict__ onev,
                             const int*   __restrict__ pairs,
                             float* __restrict__ qg,
                             float* __restrict__ baseg) {
    const int b   = blockIdx.x;
    const int tid = threadIdx.x;
    const int h = pairs[b * 2 + 0];
    const int r = pairs[b * 2 + 1];
    const float4* h4 = (const float4*)(ent  + (size_t)h * DIM);
    const float4* c4 = (const float4*)(relc + (size_t)r * DIM);
    const float4* o4 = (const float4*)(relo + (size_t)r * DIM);
    float4* q4 = (float4*)(qg + (size_t)b * DIM);
    float so = 0.f;
    for (int i = tid; i < D4; i += THREADS) {
        float4 a = h4[i], c = c4[i], o = o4[i];
        q4[i] = make_float4(a.x + c.x, a.y + c.y, a.z + c.z, a.w + c.w);
        so += o.x + o.y + o.z + o.w;
    }
    __shared__ float sred[THREADS / 64];
    for (int off = 32; off; off >>= 1) so += __shfl_down(so, off);
    if ((tid & 63) == 0) sred[tid >> 6] = so;
    __syncthreads();
    if (tid == 0)
        baseg[b] = onev[0] + 0.98f * (sred[0] + sred[1] + sred[2] + sred[3]);
}

// ---- main: thread = (1 cand x 2 batches x 200 dims); wave = 32 cands x 2 D-halves ----
// shfl_xor(32) combines halves; no LDS, no atomics. 1816 live blocks -> 7.1 waves/SIMD.
// XCD swizzle: all 4 btiles of a ctile on one XCD; per-XCD cand set ~2.9 MB (L2-resident).
template <bool USE_WS>
__global__ __launch_bounds__(THREADS)
void score_kernel(const float* __restrict__ ent,
                  const float* __restrict__ relc,
                  const float* __restrict__ relo,
                  const float* __restrict__ onev,
                  const int*   __restrict__ pairs,
                  const int*   __restrict__ cidx,
                  const float* __restrict__ qg,
                  const float* __restrict__ baseg,
                  float* __restrict__ out) {
    const int fid = blockIdx.x;
    const int xcd = fid & 7;
    const int k   = fid >> 3;
    const int bt  = k & 3;          // batch tile (8 batches)
    const int g   = k >> 2;         // 0..56
    const int ct  = xcd + 8 * g;    // candidate tile (32 cands)
    if (ct >= NCT) return;

    const int tid  = threadIdx.x;
    const int lane = tid & 63;
    const int b0 = __builtin_amdgcn_readfirstlane(bt * 8 + (tid >> 6) * 2);
    const int b1 = b0 + 1;
    const int cl   = lane & 31;     // candidate within tile
    const int half = lane >> 5;     // D-half
    const int F    = half * HF4;    // float4 base

    const int cand = ct * CT + cl;
    const int ci   = cidx[cand < NCAND ? cand : NCAND - 1];
    const float4* crow = (const float4*)(ent + (size_t)ci * DIM) + F;

    const int r0 = pairs[b0 * 2 + 1];
    const int r1 = pairs[b1 * 2 + 1];
    const float4* o0p = (const float4*)(relo + (size_t)r0 * DIM) + F;
    const float4* o1p = (const float4*)(relo + (size_t)r1 * DIM) + F;
    const float4 *q0p = nullptr, *q1p = nullptr, *h0p = nullptr, *h1p = nullptr,
                 *x0p = nullptr, *x1p = nullptr;
    if (USE_WS) {
        q0p = (const float4*)(qg + (size_t)b0 * DIM) + F;
        q1p = (const float4*)(qg + (size_t)b1 * DIM) + F;
    } else {
        h0p = (const float4*)(ent  + (size_t)pairs[b0 * 2] * DIM) + F;
        h1p = (const float4*)(ent  + (size_t)pairs[b1 * 2] * DIM) + F;
        x0p = (const float4*)(relc + (size_t)r0 * DIM) + F;
        x1p = (const float4*)(relc + (size_t)r1 * DIM) + F;
    }

    float s0 = 0.f, s1 = 0.f;       // fused score accumulators
    float oa0 = 0.f, oa1 = 0.f;     // fallback: sum of o

#define ACC(cc, qq, oo, ss)                                        \
    {                                                              \
        float d_ = (cc) - (qq);                                    \
        float m_ = fmaxf(fabsf(d_), (oo));                         \
        ss = fmaf(-0.98f, m_, fmaf(-0.02f, fabsf(d_), ss));        \
    }

#define CHUNK(ch, carr)                                                          \
    {                                                                            \
        _Pragma("unroll")                                                        \
        for (int u = 0; u < 5; ++u) {                                            \
            const int i = (ch) * 5 + u;                                          \
            const float4 o0 = o0p[i];                                            \
            const float4 o1 = o1p[i];                                            \
            float4 q0, q1;                                                       \
            if (USE_WS) {                                                        \
                q0 = q0p[i];                                                     \
                q1 = q1p[i];                                                     \
            } else {                                                             \
                float4 a0 = h0p[i], e0 = x0p[i];                                 \
                float4 a1 = h1p[i], e1 = x1p[i];                                 \
                q0 = make_float4(a0.x+e0.x, a0.y+e0.y, a0.z+e0.z, a0.w+e0.w);    \
                q1 = make_float4(a1.x+e1.x, a1.y+e1.y, a1.z+e1.z, a1.w+e1.w);    \
                oa0 += o0.x + o0.y + o0.z + o0.w;                                \
                oa1 += o1.x + o1.y + o1.z + o1.w;                                \
            }                                                                    \
            ACC(carr[u].x, q0.x, o0.x, s0) ACC(carr[u].y, q0.y, o0.y, s0)        \
            ACC(carr[u].z, q0.z, o0.z, s0) ACC(carr[u].w, q0.w, o0.w, s0)        \
            ACC(carr[u].x, q1.x, o1.x, s1) ACC(carr[u].y, q1.y, o1.y, s1)        \
            ACC(carr[u].z, q1.z, o1.z, s1) ACC(carr[u].w, q1.w, o1.w, s1)        \
        }                                                                        \
    }

    // software pipeline: prefetch next 5 f4 of candidate row while computing current
    float4 c[5], cn[5];
#pragma unroll
    for (int u = 0; u < 5; ++u) c[u] = crow[u];
#pragma unroll
    for (int ch = 0; ch < 9; ++ch) {
#pragma unroll
        for (int u = 0; u < 5; ++u) cn[u] = crow[(ch + 1) * 5 + u];
        CHUNK(ch, c)
#pragma unroll
        for (int u = 0; u < 5; ++u) c[u] = cn[u];
    }
    CHUNK(9, c)
#undef CHUNK
#undef ACC

    // combine the two D-halves within the wave
    s0 += __shfl_xor(s0, 32);
    s1 += __shfl_xor(s1, 32);
    if (!USE_WS) {
        oa0 += __shfl_xor(oa0, 32);
        oa1 += __shfl_xor(oa1, 32);
    }

    if (half == 0 && cand < NCAND) {
        float base0, base1;
        if (USE_WS) {
            base0 = baseg[b0];
            base1 = baseg[b1];
        } else {
            const float onec = onev[0];
            base0 = onec + 0.98f * oa0;
            base1 = onec + 0.98f * oa1;
        }
        out[(size_t)b0 * NCAND + cand] = base0 + s0;
        out[(size_t)b1 * NCAND + cand] = base1 + s1;
    }
}

extern "C" void kernel_launch(void* const* d_in, const int* in_sizes, int n_in,
                              void* d_out, int out_size, void* d_ws, size_t ws_size,
                              hipStream_t stream) {
    const float* ent   = (const float*)d_in[0];
    const float* relc  = (const float*)d_in[1];
    const float* relo  = (const float*)d_in[2];
    const float* onev  = (const float*)d_in[3];
    const int*   pairs = (const int*)d_in[4];
    const int*   cidx  = (const int*)d_in[5];
    float*       out   = (float*)d_out;

    const int grid = 8 * 4 * 57;    // 1824; blocks with ct>=454 exit early
    const size_t need = (size_t)(B * DIM + B) * sizeof(float);

    if (ws_size >= need) {
        float* qg    = (float*)d_ws;
        float* baseg = qg + (size_t)B * DIM;
        setup_kernel<<<B, THREADS, 0, stream>>>(ent, relc, relo, onev, pairs, qg, baseg);
        score_kernel<true><<<grid, THREADS, 0, stream>>>(
            ent, relc, relo, onev, pairs, cidx, qg, baseg, out);
    } else {
        score_kernel<false><<<grid, THREADS, 0, stream>>>(
            ent, relc, relo, onev, pairs, cidx, nullptr, nullptr, out);
    }
}

// Round 6
// 86.253 us; speedup vs baseline: 1.0006x; 1.0006x over previous
//
#include <hip/hip_runtime.h>

#define DIM     400
#define D4      100
#define QF4     25      // float4 per D-quarter (100 dims)
#define B       32
#define NCAND   14505
#define NG      907     // ceil(NCAND / 16) candidate groups of 16
#define NSTRIP  64
#define THREADS 256

// ---- setup (ws path): qg[b] = ent[head_b] + relc[rel_b]; baseg[b] = one + 0.98*sum(relo[rel_b])
__global__ void setup_kernel(const float* __restrict__ ent,
                             const float* __restrict__ relc,
                             const float* __restrict__ relo,
                             const float* __restrict__ onev,
                             const int*   __restrict__ pairs,
                             float* __restrict__ qg,
                             float* __restrict__ baseg) {
    const int b   = blockIdx.x;
    const int tid = threadIdx.x;
    const int h = pairs[b * 2 + 0];
    const int r = pairs[b * 2 + 1];
    const float4* h4 = (const float4*)(ent  + (size_t)h * DIM);
    const float4* c4 = (const float4*)(relc + (size_t)r * DIM);
    const float4* o4 = (const float4*)(relo + (size_t)r * DIM);
    float4* q4 = (float4*)(qg + (size_t)b * DIM);
    float so = 0.f;
    for (int i = tid; i < D4; i += THREADS) {
        float4 a = h4[i], c = c4[i], o = o4[i];
        q4[i] = make_float4(a.x + c.x, a.y + c.y, a.z + c.z, a.w + c.w);
        so += o.x + o.y + o.z + o.w;
    }
    __shared__ float sred[THREADS / 64];
    for (int off = 32; off; off >>= 1) so += __shfl_down(so, off);
    if ((tid & 63) == 0) sred[tid >> 6] = so;
    __syncthreads();
    if (tid == 0)
        baseg[b] = onev[0] + 0.98f * (sred[0] + sred[1] + sred[2] + sred[3]);
}

// ---- main: wave = 16 cands x 4 D-quarters; q/o register-resident (200 VGPR);
// candidate rows are the ONLY repeated memory stream. Block = 4 waves = 4 batches
// sharing one cand strip (L1 reuse); strip%8 -> XCD pins ~2.9MB cand slice per L2.
template <bool USE_WS>
__global__ __launch_bounds__(THREADS, 2)
void score_kernel(const float* __restrict__ ent,
                  const float* __restrict__ relc,
                  const float* __restrict__ relo,
                  const float* __restrict__ onev,
                  const int*   __restrict__ pairs,
                  const int*   __restrict__ cidx,
                  const float* __restrict__ qg,
                  const float* __restrict__ baseg,
                  float* __restrict__ out) {
    const int fid   = blockIdx.x;          // fid = (strip%8) + 8*(bquad + 8*(strip/8))
    const int x     = fid & 7;
    const int rest  = fid >> 3;
    const int bq    = rest & 7;
    const int strip = x + 8 * (rest >> 3);

    const int tid  = threadIdx.x;
    const int lane = tid & 63;
    const int c    = lane & 15;            // candidate within group
    const int s    = lane >> 4;            // D-quarter
    const int b    = __builtin_amdgcn_readfirstlane(bq * 4 + (tid >> 6));

    const int r = pairs[b * 2 + 1];
    const float4* op = (const float4*)(relo + (size_t)r * DIM) + s * QF4;

    float4 q[QF4], o[QF4];
    float base;
    if (USE_WS) {
        const float4* qp = (const float4*)(qg + (size_t)b * DIM) + s * QF4;
#pragma unroll
        for (int i = 0; i < QF4; ++i) { q[i] = qp[i]; o[i] = op[i]; }
        base = baseg[b];
    } else {
        const float4* hp = (const float4*)(ent  + (size_t)pairs[b * 2] * DIM) + s * QF4;
        const float4* xp = (const float4*)(relc + (size_t)r * DIM) + s * QF4;
        float oa = 0.f;
#pragma unroll
        for (int i = 0; i < QF4; ++i) {
            float4 a = hp[i], e = xp[i];
            q[i] = make_float4(a.x + e.x, a.y + e.y, a.z + e.z, a.w + e.w);
            o[i] = op[i];
            oa += o[i].x + o[i].y + o[i].z + o[i].w;
        }
        oa += __shfl_xor(oa, 16);
        oa += __shfl_xor(oa, 32);
        base = onev[0] + 0.98f * oa;
    }

#define ACC(cc, qq, oo, ss)                                        \
    {                                                              \
        float d_ = (cc) - (qq);                                    \
        float m_ = fmaxf(fabsf(d_), (oo));                         \
        ss = fmaf(-0.98f, m_, fmaf(-0.02f, fabsf(d_), ss));        \
    }

    // prime first candidate's first chunk
    int g = strip;
    {
        const int cand0 = g * 16 + c;
        const int ci0 = cidx[cand0 < NCAND ? cand0 : NCAND - 1];
        const float4* crow0 = (const float4*)(ent + (size_t)ci0 * DIM) + s * QF4;
        float4 cb[5], cn[5];
#pragma unroll
        for (int u = 0; u < 5; ++u) cb[u] = crow0[u];

        const float4* crow = crow0;
        while (g < NG) {
            const int gn    = g + NSTRIP;
            const int candn = gn * 16 + c;
            const int cin   = cidx[candn < NCAND ? candn : NCAND - 1];
            const float4* crown = (const float4*)(ent + (size_t)cin * DIM) + s * QF4;

            float acc = 0.f;
#pragma unroll
            for (int ch = 0; ch < 5; ++ch) {
#pragma unroll
                for (int u = 0; u < 5; ++u)
                    cn[u] = (ch < 4) ? crow[(ch + 1) * 5 + u] : crown[u];
#pragma unroll
                for (int u = 0; u < 5; ++u) {
                    const int i = ch * 5 + u;
                    ACC(cb[u].x, q[i].x, o[i].x, acc)
                    ACC(cb[u].y, q[i].y, o[i].y, acc)
                    ACC(cb[u].z, q[i].z, o[i].z, acc)
                    ACC(cb[u].w, q[i].w, o[i].w, acc)
                }
#pragma unroll
                for (int u = 0; u < 5; ++u) cb[u] = cn[u];
            }

            acc += __shfl_xor(acc, 16);
            acc += __shfl_xor(acc, 32);

            const int cand = g * 16 + c;
            if (lane < 16 && cand < NCAND)
                out[(size_t)b * NCAND + cand] = base + acc;

            crow = crown;
            g = gn;
        }
    }
#undef ACC
}

extern "C" void kernel_launch(void* const* d_in, const int* in_sizes, int n_in,
                              void* d_out, int out_size, void* d_ws, size_t ws_size,
                              hipStream_t stream) {
    const float* ent   = (const float*)d_in[0];
    const float* relc  = (const float*)d_in[1];
    const float* relo  = (const float*)d_in[2];
    const float* onev  = (const float*)d_in[3];
    const int*   pairs = (const int*)d_in[4];
    const int*   cidx  = (const int*)d_in[5];
    float*       out   = (float*)d_out;

    const int grid = NSTRIP * 8;    // 512
    const size_t need = (size_t)(B * DIM + B) * sizeof(float);

    if (ws_size >= need) {
        float* qg    = (float*)d_ws;
        float* baseg = qg + (size_t)B * DIM;
        setup_kernel<<<B, THREADS, 0, stream>>>(ent, relc, relo, onev, pairs, qg, baseg);
        score_kernel<true><<<grid, THREADS, 0, stream>>>(
            ent, relc, relo, onev, pairs, cidx, qg, baseg, out);
    } else {
        score_kernel<false><<<grid, THREADS, 0, stream>>>(
            ent, relc, relo, onev, pairs, cidx, nullptr, nullptr, out);
    }
}

// Round 7
// 45.825 us; speedup vs baseline: 1.8834x; 1.8822x over previous
//
#include <hip/hip_runtime.h>

#define DIM     400
#define B       32
#define NCAND   14505
#define NROUND  3627      // ceil(NCAND/4)
#define TSTRIPS 256
#define THREADS 256

// wave = 4 candidate-slots x 16 dim-lanes; lane covers dims u+16k (k=0..24)
// q/o register-resident (25+25 VGPR). Candidate rows are the only repeated stream,
// double-buffered one round ahead. No LDS, no atomics, no setup kernel.
__global__ __launch_bounds__(THREADS, 4)
void score_kernel(const float* __restrict__ ent,
                  const float* __restrict__ relc,
                  const float* __restrict__ relo,
                  const float* __restrict__ onev,
                  const int*   __restrict__ pairs,
                  const int*   __restrict__ cidx,
                  float* __restrict__ out) {
    const int fid  = blockIdx.x;
    const int xcd  = fid & 7;            // XCD pin: same strip residue -> same L2
    const int rest = fid >> 3;
    const int bq   = rest & 7;           // batch quad
    const int tc   = rest >> 3;          // 0..31
    const int t    = xcd + 8 * tc;       // strip 0..255

    const int tid  = threadIdx.x;
    const int lane = tid & 63;
    const int u    = lane & 15;          // dim phase
    const int g    = lane >> 4;          // candidate slot 0..3
    const int b    = __builtin_amdgcn_readfirstlane(bq * 4 + (tid >> 6));

    const int hd = pairs[b * 2 + 0];
    const int rl = pairs[b * 2 + 1];
    const float* hbase = ent  + (size_t)hd * DIM + u;
    const float* cbase = relc + (size_t)rl * DIM + u;
    const float* obase = relo + (size_t)rl * DIM + u;

    // ---- one-time: q,o into registers; base = one + 0.98*sum(o) ----
    float q[25], o[25];
    float oa = 0.f;
#pragma unroll
    for (int k = 0; k < 25; ++k) {
        q[k] = hbase[16 * k] + cbase[16 * k];
        o[k] = obase[16 * k];
        oa  += o[k];
    }
    oa += __shfl_xor(oa, 1);
    oa += __shfl_xor(oa, 2);
    oa += __shfl_xor(oa, 4);
    oa += __shfl_xor(oa, 8);             // sum over 16 dim-lanes = full 400-dim sum
    const float base = onev[0] + 0.98f * oa;

    auto rowp = [&](int rr) -> const float* {
        int cand = 4 * rr + g;
        int ci   = cidx[cand < NCAND ? cand : NCAND - 1];   // clamp: harmless dup
        return ent + (size_t)ci * DIM + u;
    };

#define LOADROW(buf, rr)                                   \
    {                                                      \
        const float* p_ = rowp(rr);                        \
        _Pragma("unroll")                                  \
        for (int k = 0; k < 25; ++k) buf[k] = p_[16 * k];  \
    }

#define COMPSTORE(buf, rr)                                         \
    {                                                              \
        float am = 0.f, ad = 0.f;                                  \
        _Pragma("unroll")                                          \
        for (int k = 0; k < 25; ++k) {                             \
            float d_ = buf[k] - q[k];                              \
            float a_ = fabsf(d_);                                  \
            am += fmaxf(a_, o[k]);                                 \
            ad += a_;                                              \
        }                                                          \
        float s_ = fmaf(-0.98f, am, -0.02f * ad);                  \
        s_ += __shfl_xor(s_, 1);                                   \
        s_ += __shfl_xor(s_, 2);                                   \
        s_ += __shfl_xor(s_, 4);                                   \
        s_ += __shfl_xor(s_, 8);                                   \
        const int cand_ = 4 * (rr) + g;                            \
        if (u == 0 && cand_ < NCAND)                               \
            out[(size_t)b * NCAND + cand_] = base + s_;            \
    }

    // ---- main loop: ping-pong prefetch one round ahead ----
    float bufA[25], bufB[25];
    LOADROW(bufA, t)
    for (int rr = t; rr < NROUND; rr += 2 * TSTRIPS) {
        LOADROW(bufB, rr + TSTRIPS)              // clamped past end: harmless
        COMPSTORE(bufA, rr)
        LOADROW(bufA, rr + 2 * TSTRIPS)
        if (rr + TSTRIPS < NROUND)
            COMPSTORE(bufB, rr + TSTRIPS)
    }
#undef LOADROW
#undef COMPSTORE
}

extern "C" void kernel_launch(void* const* d_in, const int* in_sizes, int n_in,
                              void* d_out, int out_size, void* d_ws, size_t ws_size,
                              hipStream_t stream) {
    const float* ent   = (const float*)d_in[0];
    const float* relc  = (const float*)d_in[1];
    const float* relo  = (const float*)d_in[2];
    const float* onev  = (const float*)d_in[3];
    const int*   pairs = (const int*)d_in[4];
    const int*   cidx  = (const int*)d_in[5];
    float*       out   = (float*)d_out;

    const int grid = 8 * 8 * 32;   // 2048 = xcd(8) * bquad(8) * strip-chunk(32)
    score_kernel<<<grid, THREADS, 0, stream>>>(ent, relc, relo, onev, pairs, cidx, out);
}

// Round 8
// 44.848 us; speedup vs baseline: 1.9244x; 1.0218x over previous
//
#include <hip/hip_runtime.h>

#define DIM     400
#define B       32
#define NCAND   14505
#define NROUND  3627      // ceil(NCAND/4)
#define TSTRIPS 256
#define THREADS 256

// wave = 4 candidate-slots x 16 dim-lanes; lane covers dims u+16k (k=0..24)
// q/o register-resident (25+25 VGPR). Candidate rows are the only repeated stream,
// double-buffered one round ahead. No LDS, no atomics, no setup kernel.
// launch_bounds(.,2): empirically the allocator budgets VGPR = 256/arg2 (R6:128, R7:64);
// arg2=2 -> 128-reg budget, fits the ~115-reg working set with ZERO spill.
__global__ __launch_bounds__(THREADS, 2)
void score_kernel(const float* __restrict__ ent,
                  const float* __restrict__ relc,
                  const float* __restrict__ relo,
                  const float* __restrict__ onev,
                  const int*   __restrict__ pairs,
                  const int*   __restrict__ cidx,
                  float* __restrict__ out) {
    const int fid  = blockIdx.x;
    const int xcd  = fid & 7;            // XCD pin: same strip residue -> same L2
    const int rest = fid >> 3;
    const int bq   = rest & 7;           // batch quad
    const int tc   = rest >> 3;          // 0..31
    const int t    = xcd + 8 * tc;       // strip 0..255

    const int tid  = threadIdx.x;
    const int lane = tid & 63;
    const int u    = lane & 15;          // dim phase
    const int g    = lane >> 4;          // candidate slot 0..3
    const int b    = __builtin_amdgcn_readfirstlane(bq * 4 + (tid >> 6));

    const int hd = pairs[b * 2 + 0];
    const int rl = pairs[b * 2 + 1];
    const float* hbase = ent  + (size_t)hd * DIM + u;
    const float* cbase = relc + (size_t)rl * DIM + u;
    const float* obase = relo + (size_t)rl * DIM + u;

    // ---- one-time: q,o into registers; base = one + 0.98*sum(o) ----
    float q[25], o[25];
    float oa = 0.f;
#pragma unroll
    for (int k = 0; k < 25; ++k) {
        q[k] = hbase[16 * k] + cbase[16 * k];
        o[k] = obase[16 * k];
        oa  += o[k];
    }
    oa += __shfl_xor(oa, 1);
    oa += __shfl_xor(oa, 2);
    oa += __shfl_xor(oa, 4);
    oa += __shfl_xor(oa, 8);             // sum over 16 dim-lanes = full 400-dim sum
    const float base = onev[0] + 0.98f * oa;

    const float* entu = ent + u;         // hoisted: row ptr = entu + ci*DIM

    auto rowp = [&](int rr) -> const float* {
        int cand = 4 * rr + g;
        int ci   = cidx[cand < NCAND ? cand : NCAND - 1];   // clamp: harmless dup
        return entu + (size_t)ci * DIM;
    };

#define LOADROW(buf, rr)                                   \
    {                                                      \
        const float* p_ = rowp(rr);                        \
        _Pragma("unroll")                                  \
        for (int k = 0; k < 25; ++k) buf[k] = p_[16 * k];  \
    }

#define COMPSTORE(buf, rr)                                         \
    {                                                              \
        float am = 0.f, ad = 0.f;                                  \
        _Pragma("unroll")                                          \
        for (int k = 0; k < 25; ++k) {                             \
            float d_ = buf[k] - q[k];                              \
            float a_ = fabsf(d_);                                  \
            am += fmaxf(a_, o[k]);                                 \
            ad += a_;                                              \
        }                                                          \
        float s_ = fmaf(-0.98f, am, -0.02f * ad);                  \
        s_ += __shfl_xor(s_, 1);                                   \
        s_ += __shfl_xor(s_, 2);                                   \
        s_ += __shfl_xor(s_, 4);                                   \
        s_ += __shfl_xor(s_, 8);                                   \
        const int cand_ = 4 * (rr) + g;                            \
        if (u == 0 && cand_ < NCAND)                               \
            out[(size_t)b * NCAND + cand_] = base + s_;            \
    }

    // ---- main loop: ping-pong prefetch one round ahead ----
    float bufA[25], bufB[25];
    LOADROW(bufA, t)
    for (int rr = t; rr < NROUND; rr += 2 * TSTRIPS) {
        LOADROW(bufB, rr + TSTRIPS)              // clamped past end: harmless
        COMPSTORE(bufA, rr)
        LOADROW(bufA, rr + 2 * TSTRIPS)
        if (rr + TSTRIPS < NROUND)
            COMPSTORE(bufB, rr + TSTRIPS)
    }
#undef LOADROW
#undef COMPSTORE
}

extern "C" void kernel_launch(void* const* d_in, const int* in_sizes, int n_in,
                              void* d_out, int out_size, void* d_ws, size_t ws_size,
                              hipStream_t stream) {
    const float* ent   = (const float*)d_in[0];
    const float* relc  = (const float*)d_in[1];
    const float* relo  = (const float*)d_in[2];
    const float* onev  = (const float*)d_in[3];
    const int*   pairs = (const int*)d_in[4];
    const int*   cidx  = (const int*)d_in[5];
    float*       out   = (float*)d_out;

    const int grid = 8 * 8 * 32;   // 2048 = xcd(8) * bquad(8) * strip-chunk(32)
    score_kernel<<<grid, THREADS, 0, stream>>>(ent, relc, relo, onev, pairs, cidx, out);
}